// Round 7
// baseline (574.322 us; speedup 1.0000x reference)
//
#include <hip/hip_runtime.h>

typedef __attribute__((ext_vector_type(8))) short short8;
typedef __attribute__((ext_vector_type(4))) float f32x4;

#define NPB   128                 // nodes per bucket
#define CAPB  2688                // max edges per bucket (mean 2046)
#define TILE  8192                // edges per tile-sort block
#define MAXB  800                 // max buckets (N <= 102400)

__device__ __forceinline__ float bfLO(unsigned u){
  union { unsigned x; float f; } c; c.x = u << 16; return c.f;
}
__device__ __forceinline__ float bfHI(unsigned u){
  union { unsigned x; float f; } c; c.x = u & 0xffff0000u; return c.f;
}
__device__ __forceinline__ unsigned short f2bf(float f){
  union { float f; unsigned u; } v; v.f = f;
  unsigned r = v.u + 0x7fffu + ((v.u >> 16) & 1u);
  return (unsigned short)(r >> 16);
}

// ---- pre-pack ALL weights into MFMA B-fragment order + zero bcnt/cursor ----
__global__ void k_wprep_all(const float* __restrict__ W_in, const float* __restrict__ convW,
                            const float* __restrict__ W_out, unsigned short* __restrict__ Bf,
                            int* __restrict__ zeroPtr, int zeroN){
  if (blockIdx.x >= 40){                       // tail blocks: zero bcnt + cursor
    int i = (blockIdx.x - 40)*256 + threadIdx.x;
    if (i < zeroN) zeroPtr[i] = 0;
    return;
  }
  const int slot = blockIdx.x >> 3;
  const int idx  = (blockIdx.x & 7)*256 + threadIdx.x;
  const float* W; int ncol;
  if (slot == 0){ W = W_in; ncol = 128; }
  else if (slot <= 3){ W = convW + (size_t)(slot-1)*128*128; ncol = 128; }
  else { W = W_out; ncol = 64; }
  const int l = idx & 63, ks = (idx >> 6) & 3, cb = idx >> 8;
  if (cb >= (ncol >> 4)) return;
  const int c  = cb*16 + (l & 15);
  const int k0 = ks*32 + ((l >> 4) << 3);
  unsigned short* o = Bf + (size_t)slot*16384 + (size_t)idx*8;
#pragma unroll
  for (int j = 0; j < 8; ++j) o[j] = f2bf(W[(size_t)(k0 + j)*ncol + c]);
}

// ---- phase 1: per-block tile sort -> dense bulk append into buckets ----
__global__ __launch_bounds__(256) void k_bucket2(const void* ei,
    int* __restrict__ bcnt, unsigned* __restrict__ buf, int E, int nbuck)
{
  __shared__ unsigned recs[TILE];
  __shared__ unsigned short recb[TILE];
  __shared__ int cnt[MAXB];
  __shared__ int offs[MAXB];
  __shared__ int ofc[MAXB];
  __shared__ int gbase[MAXB];
  __shared__ int sc[256];
  __shared__ int s_i64;

  const int tid = threadIdx.x;
  if (tid < 64){
    unsigned v = ((const unsigned*)ei)[2*tid + 1];
    unsigned long long any = __ballot(v != 0u);
    if (tid == 0) s_i64 = (any == 0ull) ? 1 : 0;
  }
  const int e0 = blockIdx.x * TILE;
  const int m = min(TILE, E - e0);
  if (m <= 0) return;

  for (int i = tid; i < nbuck; i += 256) cnt[i] = 0;
  __syncthreads();
  const bool i64 = s_i64 != 0;

  for (int i = tid; i < m; i += 256){
    int c = i64 ? (int)((const long long*)ei)[(size_t)E + e0 + i]
                : ((const int*)ei)[(size_t)E + e0 + i];
    atomicAdd(&cnt[c >> 7], 1);
  }
  __syncthreads();

  int lc[4]; int tsum = 0;
#pragma unroll
  for (int j = 0; j < 4; ++j){
    int b = tid*4 + j;
    lc[j] = (b < nbuck) ? cnt[b] : 0;
    tsum += lc[j];
  }
  sc[tid] = tsum; __syncthreads();
  for (int off = 1; off < 256; off <<= 1){
    int a = (tid >= off) ? sc[tid - off] : 0;
    __syncthreads(); sc[tid] += a; __syncthreads();
  }
  int run = sc[tid] - tsum;
#pragma unroll
  for (int j = 0; j < 4; ++j){
    int b = tid*4 + j;
    if (b < nbuck){
      offs[b] = run; ofc[b] = run;
      gbase[b] = lc[j] ? atomicAdd(&bcnt[b*16], lc[j]) : 0;
    }
    run += lc[j];
  }
  __syncthreads();

  for (int i = tid; i < m; i += 256){
    int r, c;
    if (i64){ const long long* p = (const long long*)ei; r = (int)p[e0+i]; c = (int)p[(size_t)E+e0+i]; }
    else    { const int* p = (const int*)ei;            r = p[e0+i];      c = p[(size_t)E+e0+i]; }
    int b = c >> 7;
    int pos = atomicAdd(&ofc[b], 1);
    recs[pos] = ((unsigned)(c & (NPB-1)) << 17) | (unsigned)r;
    recb[pos] = (unsigned short)b;
  }
  __syncthreads();

  for (int i = tid; i < m; i += 256){
    int b = recb[i];
    int dst = gbase[b] + (i - offs[b]);
    if (dst < CAPB) buf[(size_t)b*CAPB + dst] = recs[i];
  }
}

// ---- phase 2: per-bucket CSR build; span reserved via global cursor ----
__global__ __launch_bounds__(256) void k_csr2(const int* __restrict__ bcnt,
    const unsigned* __restrict__ buf, int2* __restrict__ nspan,
    int* __restrict__ srcl, float* __restrict__ dinv, int* __restrict__ cursor, int N){
  __shared__ unsigned recs[CAPB];
  __shared__ int cnt[NPB];
  __shared__ int ex[NPB];
  __shared__ int sc[256];
  __shared__ int s_base;
  const int b = blockIdx.x, tid = threadIdx.x;
  const int m = min(bcnt[b*16], CAPB);
  if (tid == 0) s_base = atomicAdd(cursor, m);

  if (tid < NPB) cnt[tid] = 0;
  __syncthreads();
  for (int i = tid; i < m; i += 256){
    unsigned rec = buf[(size_t)b*CAPB + i];
    recs[i] = rec;
    atomicAdd(&cnt[rec >> 17], 1);
  }
  __syncthreads();
  const int base = s_base;
  int v = (tid < NPB) ? cnt[tid] : 0;
  sc[tid] = v; __syncthreads();
  for (int off = 1; off < 256; off <<= 1){
    int a = (tid >= off) ? sc[tid - off] : 0;
    __syncthreads();
    sc[tid] += a;
    __syncthreads();
  }
  if (tid < NPB){
    int excl = sc[tid] - v;
    ex[tid] = excl;
    int g = b*NPB + tid;
    if (g < N){
      nspan[g] = make_int2(base + excl, v);
      dinv[g]  = rsqrtf((float)v + 1.0f);     // +1 self-loop
    }
  }
  __syncthreads();
  for (int i = tid; i < m; i += 256){
    unsigned rec = recs[i];
    int pos = base + atomicAdd(&ex[rec >> 17], 1);
    srcl[pos] = (int)(rec & 0x1FFFFu);
  }
}

// ---- GEMM: [nrows,128] @ [128,NCOL] from global A; used for the input layer ----
template<int NCOL, bool A_F32, bool BIAS, bool RELU, bool SCALE, bool OUT_F32>
__global__ __launch_bounds__(256) void k_mm(const void* __restrict__ Ap,
    const unsigned short* __restrict__ Bf, const float* __restrict__ bias,
    const float* __restrict__ dinv, void* __restrict__ Cp, int nrows)
{
  constexpr int NCB = NCOL/16;
  const int tid = threadIdx.x;
  const int wave = tid >> 6, l = tid & 63;
  const int lr = l & 15, lg = l >> 4;
  const int row0 = blockIdx.x*128 + wave*32;

  f32x4 acc[2][NCB];
#pragma unroll
  for (int i = 0; i < 2; ++i)
#pragma unroll
    for (int j = 0; j < NCB; ++j) acc[i][j] = f32x4{0.f, 0.f, 0.f, 0.f};

  const int r0 = row0 + lr, r1 = row0 + 16 + lr;
  const bool ok0 = r0 < nrows, ok1 = r1 < nrows;

#pragma unroll
  for (int ks = 0; ks < 4; ++ks){
    const int kbase = ks*32 + lg*8;
    short8 a0 = short8{0,0,0,0,0,0,0,0}, a1 = short8{0,0,0,0,0,0,0,0};
    if constexpr (A_F32){
      const float* A = (const float*)Ap;
      if (ok0){
        const float* p = A + (size_t)r0*128 + kbase;
        f32x4 x0 = *(const f32x4*)p, x1 = *(const f32x4*)(p + 4);
#pragma unroll
        for (int j = 0; j < 4; ++j){ a0[j] = (short)f2bf(x0[j]); a0[j+4] = (short)f2bf(x1[j]); }
      }
      if (ok1){
        const float* p = A + (size_t)r1*128 + kbase;
        f32x4 x0 = *(const f32x4*)p, x1 = *(const f32x4*)(p + 4);
#pragma unroll
        for (int j = 0; j < 4; ++j){ a1[j] = (short)f2bf(x0[j]); a1[j+4] = (short)f2bf(x1[j]); }
      }
    } else {
      const unsigned short* A = (const unsigned short*)Ap;
      if (ok0) a0 = *(const short8*)(A + (size_t)r0*128 + kbase);
      if (ok1) a1 = *(const short8*)(A + (size_t)r1*128 + kbase);
    }
#pragma unroll
    for (int cb = 0; cb < NCB; ++cb){
      short8 b = *(const short8*)(Bf + ((size_t)(cb*4 + ks)*64 + l)*8);
      acc[0][cb] = __builtin_amdgcn_mfma_f32_16x16x32_bf16(a0, b, acc[0][cb], 0, 0, 0);
      acc[1][cb] = __builtin_amdgcn_mfma_f32_16x16x32_bf16(a1, b, acc[1][cb], 0, 0, 0);
    }
  }

#pragma unroll
  for (int rb = 0; rb < 2; ++rb){
#pragma unroll
    for (int j = 0; j < 4; ++j){
      const int r = row0 + rb*16 + lg*4 + j;
      if (r >= nrows) continue;
      const float dv = SCALE ? dinv[r] : 1.0f;
#pragma unroll
      for (int cb = 0; cb < NCB; ++cb){
        const int c = cb*16 + lr;
        float v = acc[rb][cb][j];
        if constexpr (BIAS) v += bias[c];
        if constexpr (RELU) v = fmaxf(v, 0.0f);
        if constexpr (SCALE) v *= dv;
        if constexpr (OUT_F32) ((float*)Cp)[(size_t)r*NCOL + c] = v;
        else ((unsigned short*)Cp)[(size_t)r*NCOL + c] = f2bf(v);
      }
    }
  }
}

// ---- fused conv layer: gather(ĥ) -> LDS u tile -> MFMA relu(uW+b) ----
// hs holds ĥ = dinv⊙h.  u_c = dinv_c·(Σ_r ĥ_r + ĥ_c).
// !LAST: writes ĥ_next = dinv⊙relu(uW+b) (bf16).
// LAST : h3 = relu(uW+b) -> LDS -> logits = h3@W_out + b_out (f32).
template<bool LAST>
__global__ __launch_bounds__(256) void k_conv(const unsigned* __restrict__ hs,
    const int2* __restrict__ nspan, const int* __restrict__ srcl,
    const float* __restrict__ dinv, const unsigned short* __restrict__ Bf,
    const float* __restrict__ bias, const unsigned short* __restrict__ BfO,
    const float* __restrict__ bias_out, void* __restrict__ outp, int n)
{
  __shared__ char u_raw[128*256];            // 128 rows x 128 bf16, XOR-swizzled
  const int tid = threadIdx.x, wave = tid >> 6, l = tid & 63;
  const int lr = l & 15, lg = l >> 4;

  // ---- phase 1: each wave gathers its 32 nodes ----
  for (int nn = 0; nn < 32; ++nn){
    const int node = blockIdx.x*128 + wave*32 + nn;
    if (node >= n) continue;
    const int2 sp = nspan[node];
    int i = sp.x;
    const int e = sp.x + sp.y;

    unsigned v = hs[(size_t)node*64 + l];            // self-loop: ĥ_c
    float a0 = bfLO(v), a1 = bfHI(v);

    int idx = (i < e) ? srcl[min(i + l, e - 1)] : 0;
    while (i < e){
      const int cnt = min(e - i, 64);
      const int nexti = i + cnt;
      const int idxn = (nexti < e) ? srcl[min(nexti + l, e - 1)] : 0;
      int j = 0;
      for (; j + 16 <= cnt; j += 16){
        unsigned u[16];
#pragma unroll
        for (int q = 0; q < 16; ++q){
          int s = __builtin_amdgcn_readlane(idx, j + q);
          u[q] = hs[(size_t)s*64 + l];
        }
#pragma unroll
        for (int q = 0; q < 16; ++q){ a0 += bfLO(u[q]); a1 += bfHI(u[q]); }
      }
      for (; j + 8 <= cnt; j += 8){
        unsigned u[8];
#pragma unroll
        for (int q = 0; q < 8; ++q){
          int s = __builtin_amdgcn_readlane(idx, j + q);
          u[q] = hs[(size_t)s*64 + l];
        }
#pragma unroll
        for (int q = 0; q < 8; ++q){ a0 += bfLO(u[q]); a1 += bfHI(u[q]); }
      }
      for (; j + 4 <= cnt; j += 4){
        unsigned u[4];
#pragma unroll
        for (int q = 0; q < 4; ++q){
          int s = __builtin_amdgcn_readlane(idx, j + q);
          u[q] = hs[(size_t)s*64 + l];
        }
#pragma unroll
        for (int q = 0; q < 4; ++q){ a0 += bfLO(u[q]); a1 += bfHI(u[q]); }
      }
      for (; j < cnt; ++j){
        int s = __builtin_amdgcn_readlane(idx, j);
        unsigned u0 = hs[(size_t)s*64 + l];
        a0 += bfLO(u0); a1 += bfHI(u0);
      }
      i = nexti; idx = idxn;
    }
    const float dv = dinv[node];
    const int lrow = wave*32 + nn;
    unsigned pk = (unsigned)f2bf(dv*a0) | ((unsigned)f2bf(dv*a1) << 16);
    *(unsigned*)(u_raw + ((lrow*256 + l*4) ^ ((lrow & 7) << 4))) = pk;
  }
  __syncthreads();

  // ---- phase 2: MFMA u @ W from LDS ----
  f32x4 acc[2][8];
#pragma unroll
  for (int i = 0; i < 2; ++i)
#pragma unroll
    for (int j = 0; j < 8; ++j) acc[i][j] = f32x4{0.f, 0.f, 0.f, 0.f};

  const int r0l = wave*32 + lr, r1l = r0l + 16;
#pragma unroll
  for (int ks = 0; ks < 4; ++ks){
    const int off = ks*64 + lg*16;
    short8 a0 = *(const short8*)(u_raw + ((r0l*256 + off) ^ ((r0l & 7) << 4)));
    short8 a1 = *(const short8*)(u_raw + ((r1l*256 + off) ^ ((r1l & 7) << 4)));
#pragma unroll
    for (int cb = 0; cb < 8; ++cb){
      short8 b = *(const short8*)(Bf + ((size_t)(cb*4 + ks)*64 + l)*8);
      acc[0][cb] = __builtin_amdgcn_mfma_f32_16x16x32_bf16(a0, b, acc[0][cb], 0, 0, 0);
      acc[1][cb] = __builtin_amdgcn_mfma_f32_16x16x32_bf16(a1, b, acc[1][cb], 0, 0, 0);
    }
  }

  if constexpr (!LAST){
    unsigned short* H = (unsigned short*)outp;
#pragma unroll
    for (int rb = 0; rb < 2; ++rb){
#pragma unroll
      for (int j = 0; j < 4; ++j){
        const int r = blockIdx.x*128 + wave*32 + rb*16 + lg*4 + j;
        if (r >= n) continue;
        const float dv = dinv[r];
#pragma unroll
        for (int cb = 0; cb < 8; ++cb){
          const int c = cb*16 + lr;
          float v = fmaxf(acc[rb][cb][j] + bias[c], 0.0f) * dv;   // ĥ_next
          H[(size_t)r*128 + c] = f2bf(v);
        }
      }
    }
  } else {
    // ---- phase 3: h3 -> LDS (own band), then h3 @ W_out + b_out -> f32 ----
    __syncthreads();
#pragma unroll
    for (int rb = 0; rb < 2; ++rb){
#pragma unroll
      for (int j = 0; j < 4; ++j){
        const int lrow = wave*32 + rb*16 + lg*4 + j;
#pragma unroll
        for (int cb = 0; cb < 8; ++cb){
          const int c = cb*16 + lr;
          float v = fmaxf(acc[rb][cb][j] + bias[c], 0.0f);
          *(unsigned short*)(u_raw + ((lrow*256 + c*2) ^ ((lrow & 7) << 4))) = f2bf(v);
        }
      }
    }
    __syncthreads();

    f32x4 acc2[2][4];
#pragma unroll
    for (int i = 0; i < 2; ++i)
#pragma unroll
      for (int j = 0; j < 4; ++j) acc2[i][j] = f32x4{0.f, 0.f, 0.f, 0.f};

#pragma unroll
    for (int ks = 0; ks < 4; ++ks){
      const int off = ks*64 + lg*16;
      short8 a0 = *(const short8*)(u_raw + ((r0l*256 + off) ^ ((r0l & 7) << 4)));
      short8 a1 = *(const short8*)(u_raw + ((r1l*256 + off) ^ ((r1l & 7) << 4)));
#pragma unroll
      for (int cb = 0; cb < 4; ++cb){
        short8 b = *(const short8*)(BfO + ((size_t)(cb*4 + ks)*64 + l)*8);
        acc2[0][cb] = __builtin_amdgcn_mfma_f32_16x16x32_bf16(a0, b, acc2[0][cb], 0, 0, 0);
        acc2[1][cb] = __builtin_amdgcn_mfma_f32_16x16x32_bf16(a1, b, acc2[1][cb], 0, 0, 0);
      }
    }
    float* O = (float*)outp;
#pragma unroll
    for (int rb = 0; rb < 2; ++rb){
#pragma unroll
      for (int j = 0; j < 4; ++j){
        const int r = blockIdx.x*128 + wave*32 + rb*16 + lg*4 + j;
        if (r >= n) continue;
#pragma unroll
        for (int cb = 0; cb < 4; ++cb){
          const int c = cb*16 + lr;
          O[(size_t)r*64 + c] = acc2[rb][cb][j] + bias_out[c];
        }
      }
    }
  }
}

extern "C" void kernel_launch(void* const* d_in, const int* in_sizes, int n_in,
                              void* d_out, int out_size, void* d_ws, size_t ws_size,
                              hipStream_t stream)
{
  const float* x     = (const float*)d_in[0];
  const void*  ei    = d_in[1];
  const float* W_in  = (const float*)d_in[2];
  const float* b_in  = (const float*)d_in[3];
  const float* convW = (const float*)d_in[4];
  const float* convb = (const float*)d_in[5];
  const float* W_out = (const float*)d_in[6];
  const float* b_out = (const float*)d_in[7];
  float* out = (float*)d_out;

  const int N = in_sizes[0] / 128;
  const int E = in_sizes[1] / 2;
  const int NBUCK = (N + NPB - 1) / NPB;

  char* w = (char*)d_ws;
  auto alloc = [&](size_t b){ char* p = w; w += (b + 255) & ~(size_t)255; return p; };
  unsigned short* h    = (unsigned short*)alloc((size_t)N*128*2);
  unsigned short* t    = (unsigned short*)alloc((size_t)N*128*2);
  unsigned short* Bf   = (unsigned short*)alloc((size_t)5*16384*2);
  float* dinv          = (float*)alloc((size_t)N*4);
  int2* nspan          = (int2*)alloc((size_t)N*8);
  int* srcl            = (int*)alloc((size_t)E*4);
  int* bcnt            = (int*)alloc((size_t)(NBUCK*16 + 16)*4);   // + cursor tail
  unsigned* bbuf       = (unsigned*)t;     // alias: bucket buffer dead before t is live

  int* cursor = bcnt + NBUCK*16;
  const int zeroN = NBUCK*16 + 16;
  const int ZB = (zeroN + 255)/256;
  const int MB = (N + 127) / 128;

  k_wprep_all<<<40 + ZB, 256, 0, stream>>>(W_in, convW, W_out, Bf, bcnt, zeroN);
  k_bucket2<<<(E + TILE - 1)/TILE, 256, 0, stream>>>(ei, bcnt, bbuf, E, NBUCK);
  k_csr2  <<<NBUCK, 256, 0, stream>>>(bcnt, bbuf, nspan, srcl, dinv, cursor, N);

  // ĥ⁰ = dinv ⊙ relu(x @ W_in + b_in)
  k_mm<128, true, true, true, true, false><<<MB, 256, 0, stream>>>(x, Bf, b_in, dinv, h, N);

  // conv1: h -> t ; conv2: t -> h ; conv3 (+W_out): h -> out
  k_conv<false><<<MB, 256, 0, stream>>>((const unsigned*)h, nspan, srcl, dinv,
      Bf + (size_t)1*16384, convb + 0*128, nullptr, nullptr, t, N);
  k_conv<false><<<MB, 256, 0, stream>>>((const unsigned*)t, nspan, srcl, dinv,
      Bf + (size_t)2*16384, convb + 1*128, nullptr, nullptr, h, N);
  k_conv<true><<<MB, 256, 0, stream>>>((const unsigned*)h, nspan, srcl, dinv,
      Bf + (size_t)3*16384, convb + 2*128, Bf + (size_t)4*16384, b_out, out, N);
}

// Round 8
// 309.625 us; speedup vs baseline: 1.8549x; 1.8549x over previous
//
#include <hip/hip_runtime.h>

typedef __attribute__((ext_vector_type(8))) short short8;
typedef __attribute__((ext_vector_type(4))) float f32x4;

#define NPB   128                 // nodes per bucket
#define CAPB  2688                // max edges per bucket (mean 2046)
#define TILE  4096                // edges per tile-sort block
#define MAXB  800                 // max buckets (N <= 102400)

__device__ __forceinline__ float bfLO(unsigned u){
  union { unsigned x; float f; } c; c.x = u << 16; return c.f;
}
__device__ __forceinline__ float bfHI(unsigned u){
  union { unsigned x; float f; } c; c.x = u & 0xffff0000u; return c.f;
}
__device__ __forceinline__ unsigned short f2bf(float f){
  union { float f; unsigned u; } v; v.f = f;
  unsigned r = v.u + 0x7fffu + ((v.u >> 16) & 1u);
  return (unsigned short)(r >> 16);
}

// ---- pre-pack ALL weights into MFMA B-fragment order + zero bcnt/cursor ----
__global__ void k_wprep_all(const float* __restrict__ W_in, const float* __restrict__ convW,
                            const float* __restrict__ W_out, unsigned short* __restrict__ Bf,
                            int* __restrict__ zeroPtr, int zeroN){
  if (blockIdx.x >= 40){                       // tail blocks: zero bcnt + cursor
    int i = (blockIdx.x - 40)*256 + threadIdx.x;
    if (i < zeroN) zeroPtr[i] = 0;
    return;
  }
  const int slot = blockIdx.x >> 3;
  const int idx  = (blockIdx.x & 7)*256 + threadIdx.x;
  const float* W; int ncol;
  if (slot == 0){ W = W_in; ncol = 128; }
  else if (slot <= 3){ W = convW + (size_t)(slot-1)*128*128; ncol = 128; }
  else { W = W_out; ncol = 64; }
  const int l = idx & 63, ks = (idx >> 6) & 3, cb = idx >> 8;
  if (cb >= (ncol >> 4)) return;
  const int c  = cb*16 + (l & 15);
  const int k0 = ks*32 + ((l >> 4) << 3);
  unsigned short* o = Bf + (size_t)slot*16384 + (size_t)idx*8;
#pragma unroll
  for (int j = 0; j < 8; ++j) o[j] = f2bf(W[(size_t)(k0 + j)*ncol + c]);
}

// ---- GEMM body: [nrows,128] @ [128,NCOL], 128-row tile per bid, 4 waves ----
template<int NCOL, bool A_F32, bool BIAS, bool RELU, bool OUT_F32>
__device__ __forceinline__ void mm_body(int bid, const void* __restrict__ Ap,
    const unsigned short* __restrict__ Bf, const float* __restrict__ bias,
    void* __restrict__ Cp, int nrows)
{
  constexpr int NCB = NCOL/16;
  const int tid = threadIdx.x;
  const int wave = tid >> 6, l = tid & 63;
  const int lr = l & 15, lg = l >> 4;
  const int row0 = bid*128 + wave*32;

  f32x4 acc[2][NCB];
#pragma unroll
  for (int i = 0; i < 2; ++i)
#pragma unroll
    for (int j = 0; j < NCB; ++j) acc[i][j] = f32x4{0.f, 0.f, 0.f, 0.f};

  const int r0 = row0 + lr, r1 = row0 + 16 + lr;
  const bool ok0 = r0 < nrows, ok1 = r1 < nrows;

#pragma unroll
  for (int ks = 0; ks < 4; ++ks){
    const int kbase = ks*32 + lg*8;
    short8 a0 = short8{0,0,0,0,0,0,0,0}, a1 = short8{0,0,0,0,0,0,0,0};
    if constexpr (A_F32){
      const float* A = (const float*)Ap;
      if (ok0){
        const float* p = A + (size_t)r0*128 + kbase;
        f32x4 x0 = *(const f32x4*)p, x1 = *(const f32x4*)(p + 4);
#pragma unroll
        for (int j = 0; j < 4; ++j){ a0[j] = (short)f2bf(x0[j]); a0[j+4] = (short)f2bf(x1[j]); }
      }
      if (ok1){
        const float* p = A + (size_t)r1*128 + kbase;
        f32x4 x0 = *(const f32x4*)p, x1 = *(const f32x4*)(p + 4);
#pragma unroll
        for (int j = 0; j < 4; ++j){ a1[j] = (short)f2bf(x0[j]); a1[j+4] = (short)f2bf(x1[j]); }
      }
    } else {
      const unsigned short* A = (const unsigned short*)Ap;
      if (ok0) a0 = *(const short8*)(A + (size_t)r0*128 + kbase);
      if (ok1) a1 = *(const short8*)(A + (size_t)r1*128 + kbase);
    }
#pragma unroll
    for (int cb = 0; cb < NCB; ++cb){
      short8 b = *(const short8*)(Bf + ((size_t)(cb*4 + ks)*64 + l)*8);
      acc[0][cb] = __builtin_amdgcn_mfma_f32_16x16x32_bf16(a0, b, acc[0][cb], 0, 0, 0);
      acc[1][cb] = __builtin_amdgcn_mfma_f32_16x16x32_bf16(a1, b, acc[1][cb], 0, 0, 0);
    }
  }

  // C/D layout: col = lane&15, row = (lane>>4)*4 + reg
#pragma unroll
  for (int rb = 0; rb < 2; ++rb){
#pragma unroll
    for (int j = 0; j < 4; ++j){
      const int r = row0 + rb*16 + lg*4 + j;
      if (r >= nrows) continue;
#pragma unroll
      for (int cb = 0; cb < NCB; ++cb){
        const int c = cb*16 + lr;
        float v = acc[rb][cb][j];
        if constexpr (BIAS) v += bias[c];
        if constexpr (RELU) v = fmaxf(v, 0.0f);
        if constexpr (OUT_F32) ((float*)Cp)[(size_t)r*NCOL + c] = v;
        else ((unsigned short*)Cp)[(size_t)r*NCOL + c] = f2bf(v);
      }
    }
  }
}

template<int NCOL, bool A_F32, bool BIAS, bool RELU, bool OUT_F32>
__global__ __launch_bounds__(256) void k_mm_g(const void* __restrict__ Ap,
    const unsigned short* __restrict__ Bf, const float* __restrict__ bias,
    void* __restrict__ Cp, int nrows){
  mm_body<NCOL, A_F32, BIAS, RELU, OUT_F32>(blockIdx.x, Ap, Bf, bias, Cp, nrows);
}

// ---- bucket tile-sort body (per-block dtype detect; dense bulk append) ----
__device__ __forceinline__ void bucket2_body(int bid, const void* ei,
    int* __restrict__ bcnt, unsigned* __restrict__ buf, int E, int nbuck)
{
  __shared__ unsigned recs[TILE];
  __shared__ unsigned short recb[TILE];
  __shared__ int cnt[MAXB];
  __shared__ int offs[MAXB];
  __shared__ int ofc[MAXB];
  __shared__ int gbase[MAXB];
  __shared__ int sc[256];
  __shared__ int s_i64;

  const int tid = threadIdx.x;
  if (tid < 64){
    unsigned v = ((const unsigned*)ei)[2*tid + 1];
    unsigned long long any = __ballot(v != 0u);
    if (tid == 0) s_i64 = (any == 0ull) ? 1 : 0;
  }
  const int e0 = bid * TILE;
  const int m = min(TILE, E - e0);
  if (m <= 0) return;

  for (int i = tid; i < nbuck; i += 256) cnt[i] = 0;
  __syncthreads();
  const bool i64 = s_i64 != 0;

  for (int i = tid; i < m; i += 256){
    int c = i64 ? (int)((const long long*)ei)[(size_t)E + e0 + i]
                : ((const int*)ei)[(size_t)E + e0 + i];
    atomicAdd(&cnt[c >> 7], 1);
  }
  __syncthreads();

  int lc[4]; int tsum = 0;
#pragma unroll
  for (int j = 0; j < 4; ++j){
    int b = tid*4 + j;
    lc[j] = (b < nbuck) ? cnt[b] : 0;
    tsum += lc[j];
  }
  sc[tid] = tsum; __syncthreads();
  for (int off = 1; off < 256; off <<= 1){
    int a = (tid >= off) ? sc[tid - off] : 0;
    __syncthreads(); sc[tid] += a; __syncthreads();
  }
  int run = sc[tid] - tsum;
#pragma unroll
  for (int j = 0; j < 4; ++j){
    int b = tid*4 + j;
    if (b < nbuck){
      offs[b] = run; ofc[b] = run;
      gbase[b] = lc[j] ? atomicAdd(&bcnt[b*16], lc[j]) : 0;
    }
    run += lc[j];
  }
  __syncthreads();

  for (int i = tid; i < m; i += 256){
    int r, c;
    if (i64){ const long long* p = (const long long*)ei; r = (int)p[e0+i]; c = (int)p[(size_t)E+e0+i]; }
    else    { const int* p = (const int*)ei;            r = p[e0+i];      c = p[(size_t)E+e0+i]; }
    int b = c >> 7;
    int pos = atomicAdd(&ofc[b], 1);
    recs[pos] = ((unsigned)(c & (NPB-1)) << 17) | (unsigned)r;
    recb[pos] = (unsigned short)b;
  }
  __syncthreads();

  for (int i = tid; i < m; i += 256){
    int b = recb[i];
    int dst = gbase[b] + (i - offs[b]);
    if (dst < CAPB) buf[(size_t)b*CAPB + dst] = recs[i];
  }
}

// ---- per-bucket CSR build body; span reserved via global cursor ----
__device__ __forceinline__ void csr2_body(int b, const int* __restrict__ bcnt,
    const unsigned* __restrict__ buf, int2* __restrict__ nspan,
    int* __restrict__ srcl, float* __restrict__ dinv, int* __restrict__ cursor, int N)
{
  __shared__ unsigned recs[CAPB];
  __shared__ int cnt[NPB];
  __shared__ int ex[NPB];
  __shared__ int sc[256];
  __shared__ int s_base;
  const int tid = threadIdx.x;
  const int m = min(bcnt[b*16], CAPB);
  if (tid == 0) s_base = atomicAdd(cursor, m);

  if (tid < NPB) cnt[tid] = 0;
  __syncthreads();
  for (int i = tid; i < m; i += 256){
    unsigned rec = buf[(size_t)b*CAPB + i];
    recs[i] = rec;
    atomicAdd(&cnt[rec >> 17], 1);
  }
  __syncthreads();
  const int base = s_base;
  int v = (tid < NPB) ? cnt[tid] : 0;
  sc[tid] = v; __syncthreads();
  for (int off = 1; off < 256; off <<= 1){
    int a = (tid >= off) ? sc[tid - off] : 0;
    __syncthreads();
    sc[tid] += a;
    __syncthreads();
  }
  if (tid < NPB){
    int excl = sc[tid] - v;
    ex[tid] = excl;
    int g = b*NPB + tid;
    if (g < N){
      nspan[g] = make_int2(base + excl, v);
      dinv[g]  = rsqrtf((float)v + 1.0f);     // +1 self-loop
    }
  }
  __syncthreads();
  for (int i = tid; i < m; i += 256){
    unsigned rec = recs[i];
    int pos = base + atomicAdd(&ex[rec >> 17], 1);
    srcl[pos] = (int)(rec & 0x1FFFFu);
  }
}

// ---- fat 1: mm_in (h0 = relu(x@W_in+b), unscaled)  ||  bucket tile-sort ----
__global__ __launch_bounds__(256, 4) void k_fat1(const float* __restrict__ x,
    const unsigned short* __restrict__ Bf, const float* __restrict__ b_in,
    unsigned short* __restrict__ h, const void* ei, int* __restrict__ bcnt,
    unsigned* __restrict__ bbuf, int E, int nbuck, int N, int MB)
{
  if ((int)blockIdx.x < MB)
    mm_body<128, true, true, true, false>(blockIdx.x, x, Bf, b_in, h, N);
  else
    bucket2_body(blockIdx.x - MB, ei, bcnt, bbuf, E, nbuck);
}

// ---- fat 2: mm_conv1 (t = h0 @ W1, plain)  ||  CSR build ----
__global__ __launch_bounds__(256, 4) void k_fat2(const unsigned short* __restrict__ h,
    const unsigned short* __restrict__ Bf1, unsigned short* __restrict__ t,
    const int* __restrict__ bcnt, const unsigned* __restrict__ bbuf,
    int2* __restrict__ nspan, int* __restrict__ srcl, float* __restrict__ dinv,
    int* __restrict__ cursor, int N, int MB)
{
  if ((int)blockIdx.x < MB)
    mm_body<128, false, false, false, false>(blockIdx.x, h, Bf1, nullptr, t, N);
  else
    csr2_body(blockIdx.x - MB, bcnt, bbuf, nspan, srcl, dinv, cursor, N);
}

// ---- aggregation: one wave per node ----
// SCALED: per-edge dinv[s] fmac (t rows unscaled); else t rows pre-scaled.
// u = dinv_c*(acc); o = relu(u + bias); HNEXT: write dinv_c*o else o.
template<bool SCALED, bool HNEXT>
__global__ __launch_bounds__(256, 8) void k_agg(const unsigned* __restrict__ t,
    const int2* __restrict__ nspan, const int* __restrict__ srcl,
    const float* __restrict__ dinv, const float* __restrict__ bias,
    unsigned* __restrict__ hout, int n)
{
  const int node = blockIdx.x*4 + (threadIdx.x >> 6);
  if (node >= n) return;
  const int l = threadIdx.x & 63;

  const int2 sp = nspan[node];
  int i = sp.x;
  const int e = sp.x + sp.y;
  const float dvc = dinv[node];

  unsigned v = t[(size_t)node*64 + l];                 // self-loop term
  float a0, a1;
  if constexpr (SCALED){ a0 = dvc*bfLO(v); a1 = dvc*bfHI(v); }
  else                 { a0 = bfLO(v);     a1 = bfHI(v); }

  if constexpr (SCALED){
    // VGPR-indexed gather + per-edge dinv broadcast load + fmac
    int idx = (i < e) ? srcl[min(i + l, e - 1)] : 0;
    while (i < e){
      const int cnt = min(e - i, 64);
      const int nexti = i + cnt;
      const int idxn = (nexti < e) ? srcl[min(nexti + l, e - 1)] : 0;
      int j = 0;
      for (; j + 8 <= cnt; j += 8){
        int sv[8]; unsigned u[8]; float dv[8];
#pragma unroll
        for (int q = 0; q < 8; ++q) sv[q] = __shfl(idx, j + q);
#pragma unroll
        for (int q = 0; q < 8; ++q){ u[q] = t[(size_t)sv[q]*64 + l]; dv[q] = dinv[sv[q]]; }
#pragma unroll
        for (int q = 0; q < 8; ++q){
          a0 = fmaf(dv[q], bfLO(u[q]), a0);
          a1 = fmaf(dv[q], bfHI(u[q]), a1);
        }
      }
      for (; j + 4 <= cnt; j += 4){
        int sv[4]; unsigned u[4]; float dv[4];
#pragma unroll
        for (int q = 0; q < 4; ++q) sv[q] = __shfl(idx, j + q);
#pragma unroll
        for (int q = 0; q < 4; ++q){ u[q] = t[(size_t)sv[q]*64 + l]; dv[q] = dinv[sv[q]]; }
#pragma unroll
        for (int q = 0; q < 4; ++q){
          a0 = fmaf(dv[q], bfLO(u[q]), a0);
          a1 = fmaf(dv[q], bfHI(u[q]), a1);
        }
      }
      for (; j < cnt; ++j){
        int s = __shfl(idx, j);
        unsigned u0 = t[(size_t)s*64 + l];
        float dv0 = dinv[s];
        a0 = fmaf(dv0, bfLO(u0), a0);
        a1 = fmaf(dv0, bfHI(u0), a1);
      }
      i = nexti; idx = idxn;
    }
  } else {
    // SGPR (readlane) gather addressing, 16-deep
    int idx = (i < e) ? srcl[min(i + l, e - 1)] : 0;
    while (i < e){
      const int cnt = min(e - i, 64);
      const int nexti = i + cnt;
      const int idxn = (nexti < e) ? srcl[min(nexti + l, e - 1)] : 0;
      int j = 0;
      for (; j + 16 <= cnt; j += 16){
        unsigned u[16];
#pragma unroll
        for (int q = 0; q < 16; ++q){
          int s = __builtin_amdgcn_readlane(idx, j + q);
          u[q] = t[(size_t)s*64 + l];
        }
#pragma unroll
        for (int q = 0; q < 16; ++q){ a0 += bfLO(u[q]); a1 += bfHI(u[q]); }
      }
      for (; j + 8 <= cnt; j += 8){
        unsigned u[8];
#pragma unroll
        for (int q = 0; q < 8; ++q){
          int s = __builtin_amdgcn_readlane(idx, j + q);
          u[q] = t[(size_t)s*64 + l];
        }
#pragma unroll
        for (int q = 0; q < 8; ++q){ a0 += bfLO(u[q]); a1 += bfHI(u[q]); }
      }
      for (; j + 4 <= cnt; j += 4){
        unsigned u[4];
#pragma unroll
        for (int q = 0; q < 4; ++q){
          int s = __builtin_amdgcn_readlane(idx, j + q);
          u[q] = t[(size_t)s*64 + l];
        }
#pragma unroll
        for (int q = 0; q < 4; ++q){ a0 += bfLO(u[q]); a1 += bfHI(u[q]); }
      }
      for (; j < cnt; ++j){
        int s = __builtin_amdgcn_readlane(idx, j);
        unsigned u0 = t[(size_t)s*64 + l];
        a0 += bfLO(u0); a1 += bfHI(u0);
      }
      i = nexti; idx = idxn;
    }
  }

  float o0 = fmaxf(fmaf(dvc, a0, bias[2*l]),     0.0f);
  float o1 = fmaxf(fmaf(dvc, a1, bias[2*l + 1]), 0.0f);
  if constexpr (HNEXT){ o0 *= dvc; o1 *= dvc; }
  hout[(size_t)node*64 + l] = (unsigned)f2bf(o0) | ((unsigned)f2bf(o1) << 16);
}

extern "C" void kernel_launch(void* const* d_in, const int* in_sizes, int n_in,
                              void* d_out, int out_size, void* d_ws, size_t ws_size,
                              hipStream_t stream)
{
  const float* x     = (const float*)d_in[0];
  const void*  ei    = d_in[1];
  const float* W_in  = (const float*)d_in[2];
  const float* b_in  = (const float*)d_in[3];
  const float* convW = (const float*)d_in[4];
  const float* convb = (const float*)d_in[5];
  const float* W_out = (const float*)d_in[6];
  const float* b_out = (const float*)d_in[7];
  float* out = (float*)d_out;

  const int N = in_sizes[0] / 128;
  const int E = in_sizes[1] / 2;
  const int NBUCK = (N + NPB - 1) / NPB;

  char* w = (char*)d_ws;
  auto alloc = [&](size_t b){ char* p = w; w += (b + 255) & ~(size_t)255; return p; };
  unsigned short* h    = (unsigned short*)alloc((size_t)N*128*2);
  unsigned short* t    = (unsigned short*)alloc((size_t)N*128*2);
  unsigned short* Bf   = (unsigned short*)alloc((size_t)5*16384*2);
  float* dinv          = (float*)alloc((size_t)N*4);
  int2* nspan          = (int2*)alloc((size_t)N*8);
  int* srcl            = (int*)alloc((size_t)E*4);
  int* bcnt            = (int*)alloc((size_t)(NBUCK*16 + 16)*4);   // + cursor tail
  unsigned* bbuf       = (unsigned*)d_out;   // scratch: dead before logits written

  int* cursor = bcnt + NBUCK*16;
  const int zeroN = NBUCK*16 + 16;
  const int ZB = (zeroN + 255)/256;
  const int MB = (N + 127) / 128;
  const int NB2 = (E + TILE - 1)/TILE;

  // 1) pack weights + zero counters
  k_wprep_all<<<40 + ZB, 256, 0, stream>>>(W_in, convW, W_out, Bf, bcnt, zeroN);
  // 2) mm_in (no dinv dependency)  ||  bucket tile-sort
  k_fat1<<<MB + NB2, 256, 0, stream>>>(x, Bf, b_in, h, ei, bcnt, bbuf, E, NBUCK, N, MB);
  // 3) t = h0 @ W1  ||  CSR build (srcl, nspan, dinv)
  k_fat2<<<MB + NBUCK, 256, 0, stream>>>(h, Bf + (size_t)1*16384, t, bcnt, bbuf,
                                         nspan, srcl, dinv, cursor, N, MB);
  // 4) layer 1 aggregate (per-edge dinv), write h1_hat = dinv*relu(u+b)
  k_agg<true, true><<<(N + 3)/4, 256, 0, stream>>>((const unsigned*)t, nspan, srcl, dinv,
                                                   convb + 0*128, (unsigned*)h, N);
  // 5) t = h1_hat @ W2
  k_mm_g<128, false, false, false, false><<<MB, 256, 0, stream>>>(h, Bf + (size_t)2*16384, nullptr, t, N);
  // 6) layer 2 aggregate, write h2_hat
  k_agg<false, true><<<(N + 3)/4, 256, 0, stream>>>((const unsigned*)t, nspan, srcl, dinv,
                                                    convb + 1*128, (unsigned*)h, N);
  // 7) t = h2_hat @ W3
  k_mm_g<128, false, false, false, false><<<MB, 256, 0, stream>>>(h, Bf + (size_t)3*16384, nullptr, t, N);
  // 8) layer 3 aggregate, write h3 (unscaled)
  k_agg<false, false><<<(N + 3)/4, 256, 0, stream>>>((const unsigned*)t, nspan, srcl, dinv,
                                                     convb + 2*128, (unsigned*)h, N);
  // 9) logits = h3 @ W_out + b_out (f32)
  k_mm_g<64, false, true, false, true><<<MB, 256, 0, stream>>>(h, Bf + (size_t)4*16384, b_out, out, N);
}